// Round 7
// baseline (124.660 us; speedup 1.0000x reference)
//
#include <hip/hip_runtime.h>
#include <hip/hip_cooperative_groups.h>
#include <math.h>

namespace cg = cooperative_groups;

#define NN 512   // nodes
#define MM 512   // edges
#define DD 128   // emb dim
#define HH 256   // hidden

typedef float     v4f __attribute__((ext_vector_type(4)));
typedef _Float16  h8  __attribute__((ext_vector_type(8)));
typedef _Float16  h2  __attribute__((ext_vector_type(2)));

#define CT 8192     // pairs: C-tile base (halves)
#define WT 16384    // pairs: w2 base (halves)

__device__ inline float dot8(h8 w, h8 a, h8 c, float acc) {
    h8 s = a + c;
    s = __builtin_elementwise_max(s, (h8)(_Float16)0.f);
    union { h8 v; h2 p[4]; } su, wu;
    su.v = s; wu.v = w;
    acc = __builtin_amdgcn_fdot2(su.p[0], wu.p[0], acc, false);
    acc = __builtin_amdgcn_fdot2(su.p[1], wu.p[1], acc, false);
    acc = __builtin_amdgcn_fdot2(su.p[2], wu.p[2], acc, false);
    acc = __builtin_amdgcn_fdot2(su.p[3], wu.p[3], acc, false);
    return acc;
}

// ---------------------------------------------------------------------------
// One cooperative kernel, 256 blocks x 256 threads (exactly 1 block/CU —
// within the 64 KB-budget co-residency limit at 39.4 KB LDS; R3's failure
// was 1024 blocks > the 256-block limit).
// Stage phase: b<128 -> edge-quad (single-pass scan + gather-mean + GEMV),
//              b>=128 -> node-quad GEMV. W1 tiled via LDS (XOR-swizzled),
//              4-wave k-split, cross-wave reduce. A/C stored fp16.
// grid.sync()
// Pairs phase: 32x32 tile/block, 4x4 register blocking, fp16 LDS tiles,
//              chunk-XOR swizzle (bandwidth-floor b128 reads), v_dot2_f32_f16.
// ---------------------------------------------------------------------------
__global__ __launch_bounds__(256) void k_fused(
    const float* __restrict__ X, const int* __restrict__ V,
    const int* __restrict__ E, const float* __restrict__ W1,
    const float* __restrict__ b1, const float* __restrict__ W2,
    const float* __restrict__ b2, _Float16* __restrict__ A,
    _Float16* __restrict__ C, float* __restrict__ out, int ninc)
{
    __shared__ union {
        int      lst[4][2048];      // stage: V-indices per edge (cap 2048 ea)
        float4   w1t[64][32];       // GEMV: W1 tile (swizzled), 32 KB
        _Float16 pt[WT + 256];      // pairs: A/C tiles + w2, 33.3 KB
    } u;
    __shared__ float xr[4][128];    // 4 source rows (X rows or eX means)
    __shared__ float red[16][64];   // GEMV cross-wave partials
    __shared__ int   cnt4[4];

    const int b = blockIdx.x;
    const int t = threadIdx.x;
    const int w = t >> 6, lane = t & 63;
    const bool edge = (b < 128);

    // ======================= stage phase =======================
    if (edge) {
        const int e0 = b * 4;
        if (t < 4) cnt4[t] = 0;
        __syncthreads();
        // single-pass scan: place V directly, statically partitioned list
        const int nq = ninc >> 2;
        for (int c = t; c < nq; c += 256) {
            int4 e4 = ((const int4*)E)[c];
            int4 v4 = ((const int4*)V)[c];
            int d;
            d = e4.x - e0; if ((unsigned)d < 4u) u.lst[d][atomicAdd(&cnt4[d], 1)] = v4.x;
            d = e4.y - e0; if ((unsigned)d < 4u) u.lst[d][atomicAdd(&cnt4[d], 1)] = v4.y;
            d = e4.z - e0; if ((unsigned)d < 4u) u.lst[d][atomicAdd(&cnt4[d], 1)] = v4.z;
            d = e4.w - e0; if ((unsigned)d < 4u) u.lst[d][atomicAdd(&cnt4[d], 1)] = v4.w;
        }
        __syncthreads();
        // gather-mean: wave w -> edge e0+w; lane covers dims {lane, lane+64}
        const int cnt = cnt4[w];
        const int* l  = u.lst[w];
        float s0a=0.f,s0b=0.f,s0c=0.f,s0d=0.f, s1a=0.f,s1b=0.f,s1c=0.f,s1d=0.f;
        int j = 0;
        for (; j + 4 <= cnt; j += 4) {
            int v0 = l[j], v1 = l[j+1], v2 = l[j+2], v3 = l[j+3];
            s0a += X[v0*DD + lane];      s1a += X[v0*DD + 64 + lane];
            s0b += X[v1*DD + lane];      s1b += X[v1*DD + 64 + lane];
            s0c += X[v2*DD + lane];      s1c += X[v2*DD + 64 + lane];
            s0d += X[v3*DD + lane];      s1d += X[v3*DD + 64 + lane];
        }
        for (; j < cnt; ++j) {
            int v = l[j];
            s0a += X[v*DD + lane];       s1a += X[v*DD + 64 + lane];
        }
        float inv = cnt > 0 ? 1.0f / (float)cnt : 0.0f;
        xr[w][lane]    = (s0a+s0b+s0c+s0d) * inv;
        xr[w][lane+64] = (s1a+s1b+s1c+s1d) * inv;
        __syncthreads();                 // xr ready; lst reads done (union safe)
    } else {
        const int r0 = (b - 128) * 4;
        ((float*)xr)[t]       = X[r0*DD + t];
        ((float*)xr)[t + 256] = X[r0*DD + 256 + t];
        __syncthreads();
    }

    {
        const int r0row = edge ? b*4 : (b-128)*4;
        const int koff  = edge ? DD : 0;
        _Float16* Out   = edge ? C : A;

        #pragma unroll 1
        for (int p = 0; p < 4; ++p) {
            const int h0 = p * 64;
            // stage W1 tile (64 h x 32 float4-chunks), coalesced global reads
            #pragma unroll
            for (int q = 0; q < 8; ++q) {
                int c  = q * 256 + t;
                int h  = c >> 5, kq = c & 31;
                u.w1t[h][kq ^ (h & 31)] =
                    *(const float4*)&W1[(h0 + h) * (2*DD) + koff + kq * 4];
            }
            __syncthreads();
            // compute: wave w -> k-quarter (8 chunks), lane -> h
            v4f acc0 = (v4f)(0.f), acc1 = (v4f)(0.f), acc2 = (v4f)(0.f), acc3 = (v4f)(0.f);
            #pragma unroll
            for (int i = 0; i < 8; ++i) {
                int kq = w * 8 + i;
                v4f wv = *(const v4f*)&u.w1t[lane][kq ^ (lane & 31)];
                acc0 += wv * (*(const v4f*)&xr[0][kq*4]);
                acc1 += wv * (*(const v4f*)&xr[1][kq*4]);
                acc2 += wv * (*(const v4f*)&xr[2][kq*4]);
                acc3 += wv * (*(const v4f*)&xr[3][kq*4]);
            }
            red[w*4 + 0][lane] = acc0.x + acc0.y + acc0.z + acc0.w;
            red[w*4 + 1][lane] = acc1.x + acc1.y + acc1.z + acc1.w;
            red[w*4 + 2][lane] = acc2.x + acc2.y + acc2.z + acc2.w;
            red[w*4 + 3][lane] = acc3.x + acc3.y + acc3.z + acc3.w;
            __syncthreads();
            float s = red[w][lane] + red[4 + w][lane] + red[8 + w][lane] + red[12 + w][lane];
            if (edge) s += b1[h0 + lane];
            Out[(r0row + w) * HH + h0 + lane] = (_Float16)s;
            __syncthreads();
        }
    }

    cg::this_grid().sync();              // device-scope fence: A/C visible

    // ======================= pairs phase =======================
    {
        const int tn0 = (b >> 4) * 32;
        const int tm0 = (b & 15) * 32;

        u.pt[WT + t] = (_Float16)W2[t];
        #pragma unroll
        for (int q = 0; q < 8; ++q) {
            int g   = q * 256 + t;           // 0..2047
            int row = g >> 5, cc = g & 31, r = row & 31;
            int dst = (row < 32 ? 0 : CT) + r * 256 + ((cc ^ (r >> 2)) << 3);
            const _Float16* src = (row < 32) ? A + (tn0 + r) * HH + cc * 8
                                             : C + (tm0 + r) * HH + cc * 8;
            *(h8*)&u.pt[dst] = *(const h8*)src;
        }
        __syncthreads();

        const int qa = lane & 7,  ra = 4 * qa;
        const int qc = lane >> 3, rc = 4 * qc;
        const int h0 = w * 64;

        float acc[4][4];
        #pragma unroll
        for (int i = 0; i < 4; ++i)
            #pragma unroll
            for (int j = 0; j < 4; ++j) acc[i][j] = 0.f;

        #pragma unroll
        for (int hh = 0; hh < 64; hh += 8) {
            int h  = h0 + hh;
            int cc = h >> 3;
            int sa = (cc ^ qa) << 3;
            int sc = (cc ^ qc) << 3;
            h8 wv = *(const h8*)&u.pt[WT + h];
            h8 av[4], cv[4];
            #pragma unroll
            for (int i = 0; i < 4; ++i) av[i] = *(const h8*)&u.pt[(ra + i) * 256 + sa];
            #pragma unroll
            for (int j = 0; j < 4; ++j) cv[j] = *(const h8*)&u.pt[CT + (rc + j) * 256 + sc];
            #pragma unroll
            for (int i = 0; i < 4; ++i)
                #pragma unroll
                for (int j = 0; j < 4; ++j)
                    acc[i][j] = dot8(wv, av[i], cv[j], acc[i][j]);
        }

        __syncthreads();
        float* red2 = (float*)u.pt;          // [w][32 rows][36]
        #pragma unroll
        for (int i = 0; i < 4; ++i) {
            float4 f;
            f.x = acc[i][0]; f.y = acc[i][1]; f.z = acc[i][2]; f.w = acc[i][3];
            *(float4*)&red2[w * 1152 + (ra + i) * 36 + rc] = f;
        }
        __syncthreads();

        const int rr = t >> 3;               // 0..31
        const int c4 = (t & 7) * 4;          // 0,4,...,28
        v4f s = *(const v4f*)&red2[rr * 36 + c4];
        s += *(const v4f*)&red2[1152 + rr * 36 + c4];
        s += *(const v4f*)&red2[2304 + rr * 36 + c4];
        s += *(const v4f*)&red2[3456 + rr * 36 + c4];
        const float b2v = b2[0];
        float4 o;
        float* op = &o.x;
        #pragma unroll
        for (int k = 0; k < 4; ++k) {
            float logit = s[k] + b2v;
            float p = 1.0f / (1.0f + __expf(-logit));
            op[k] = fminf(fmaxf(p, 1e-6f), 1.0f - 1e-6f);
        }
        *(float4*)&out[(tn0 + rr) * MM + tm0 + c4] = o;
    }
}

extern "C" void kernel_launch(void* const* d_in, const int* in_sizes, int n_in,
                              void* d_out, int out_size, void* d_ws, size_t ws_size,
                              hipStream_t stream)
{
    const float* X  = (const float*)d_in[0];
    const int*   V  = (const int*)d_in[1];
    const int*   E  = (const int*)d_in[2];
    const float* W1 = (const float*)d_in[3];
    const float* b1 = (const float*)d_in[4];
    const float* W2 = (const float*)d_in[5];
    const float* b2 = (const float*)d_in[6];

    _Float16* A = (_Float16*)d_ws;
    _Float16* C = A + NN * HH;
    float* out  = (float*)d_out;
    int ninc    = in_sizes[1];   // 8192

    void* args[] = {(void*)&X, (void*)&V, (void*)&E, (void*)&W1, (void*)&b1,
                    (void*)&W2, (void*)&b2, (void*)&A, (void*)&C, (void*)&out,
                    (void*)&ninc};
    hipLaunchCooperativeKernel((void*)k_fused, dim3(256), dim3(256), args, 0, stream);
}

// Round 8
// 82.524 us; speedup vs baseline: 1.5106x; 1.5106x over previous
//
#include <hip/hip_runtime.h>
#include <math.h>

#define NN 512   // nodes
#define MM 512   // edges
#define DD 128   // emb dim
#define HH 256   // hidden

typedef float     v4f __attribute__((ext_vector_type(4)));
typedef _Float16  h8  __attribute__((ext_vector_type(8)));
typedef _Float16  h2  __attribute__((ext_vector_type(2)));

// ws: A[n][h] (fp16), C[m][h] (fp16). A = X.W1a^T, C = b1 + eX.W1b^T.
// NOTE (R7): cooperative grid.sync() costs ~40us at 256 blocks on gfx950
// (8% VALUBusy over a 45us dispatch = idle spin + device fence). Two
// dependent graph launches are far cheaper. Do not re-fuse.

// ---------------------------------------------------------------------------
// k_stage: 256 blocks. b<128 -> edge-quad (single-pass scan+gather-mean+GEMV),
//          b>=128 -> node-quad (4 X rows: GEMV). Unified W1-tiled GEMV:
//   - W1 tile 64h x 128k staged to LDS, XOR-swizzled float4 slots
//     (kq ^ (h&31)) -> bandwidth-floor write+read
//   - 4 waves k-split (8 chunks each), LDS cross-wave reduce
// ---------------------------------------------------------------------------
__global__ __launch_bounds__(256) void k_stage(
    const float* __restrict__ X, const int* __restrict__ V,
    const int* __restrict__ E, const float* __restrict__ W1,
    const float* __restrict__ b1, _Float16* __restrict__ A,
    _Float16* __restrict__ C, int ninc)
{
    __shared__ union {
        int    lst[4][2048];       // edge phase: V-indices per edge (cap 2048)
        float4 w1t[64][32];        // GEMV phase: W1 tile (swizzled), 32 KB
    } u;
    __shared__ float xr[4][128];   // 4 source rows (X rows or eX means)
    __shared__ float red[16][64];  // cross-wave partials [w*4+r][h]
    __shared__ int   cnt4[4];

    const int b = blockIdx.x;
    const int t = threadIdx.x;
    const int w = t >> 6, lane = t & 63;
    const bool edge = (b < 128);

    if (edge) {
        const int e0 = b * 4;
        if (t < 4) cnt4[t] = 0;
        __syncthreads();
        // single-pass scan: place V directly into statically partitioned list
        const int nq = ninc >> 2;
        for (int c = t; c < nq; c += 256) {
            int4 e4 = ((const int4*)E)[c];
            int4 v4 = ((const int4*)V)[c];
            int d;
            d = e4.x - e0; if ((unsigned)d < 4u) u.lst[d][atomicAdd(&cnt4[d], 1)] = v4.x;
            d = e4.y - e0; if ((unsigned)d < 4u) u.lst[d][atomicAdd(&cnt4[d], 1)] = v4.y;
            d = e4.z - e0; if ((unsigned)d < 4u) u.lst[d][atomicAdd(&cnt4[d], 1)] = v4.z;
            d = e4.w - e0; if ((unsigned)d < 4u) u.lst[d][atomicAdd(&cnt4[d], 1)] = v4.w;
        }
        __syncthreads();
        // gather-mean: wave w -> edge e0+w; lane covers dims {lane, lane+64};
        // 4-deep unroll keeps 8 global loads in flight per lane.
        const int cnt = cnt4[w];
        const int* l  = u.lst[w];
        float s0a=0.f,s0b=0.f,s0c=0.f,s0d=0.f, s1a=0.f,s1b=0.f,s1c=0.f,s1d=0.f;
        int j = 0;
        for (; j + 4 <= cnt; j += 4) {
            int v0 = l[j], v1 = l[j+1], v2 = l[j+2], v3 = l[j+3];
            s0a += X[v0*DD + lane];      s1a += X[v0*DD + 64 + lane];
            s0b += X[v1*DD + lane];      s1b += X[v1*DD + 64 + lane];
            s0c += X[v2*DD + lane];      s1c += X[v2*DD + 64 + lane];
            s0d += X[v3*DD + lane];      s1d += X[v3*DD + 64 + lane];
        }
        for (; j < cnt; ++j) {
            int v = l[j];
            s0a += X[v*DD + lane];       s1a += X[v*DD + 64 + lane];
        }
        float inv = cnt > 0 ? 1.0f / (float)cnt : 0.0f;
        xr[w][lane]    = (s0a+s0b+s0c+s0d) * inv;
        xr[w][lane+64] = (s1a+s1b+s1c+s1d) * inv;
        __syncthreads();                 // xr ready; lst reads done (union safe)
    } else {
        const int r0 = (b - 128) * 4;
        ((float*)xr)[t]       = X[r0*DD + t];
        ((float*)xr)[t + 256] = X[r0*DD + 256 + t];
        __syncthreads();
    }

    const int r0row = edge ? b*4 : (b-128)*4;
    const int koff  = edge ? DD : 0;
    _Float16* Out   = edge ? C : A;

    #pragma unroll 1
    for (int p = 0; p < 4; ++p) {
        const int h0 = p * 64;
        // stage W1 tile (64 h x 32 float4-chunks), coalesced global reads
        #pragma unroll
        for (int q = 0; q < 8; ++q) {
            int c  = q * 256 + t;
            int h  = c >> 5, kq = c & 31;
            u.w1t[h][kq ^ (h & 31)] =
                *(const float4*)&W1[(h0 + h) * (2*DD) + koff + kq * 4];
        }
        __syncthreads();
        // compute: wave w -> k-quarter (8 chunks), lane -> h
        v4f acc0 = (v4f)(0.f), acc1 = (v4f)(0.f), acc2 = (v4f)(0.f), acc3 = (v4f)(0.f);
        #pragma unroll
        for (int i = 0; i < 8; ++i) {
            int kq = w * 8 + i;
            v4f wv = *(const v4f*)&u.w1t[lane][kq ^ (lane & 31)];
            acc0 += wv * (*(const v4f*)&xr[0][kq*4]);   // xr: wave-uniform -> broadcast
            acc1 += wv * (*(const v4f*)&xr[1][kq*4]);
            acc2 += wv * (*(const v4f*)&xr[2][kq*4]);
            acc3 += wv * (*(const v4f*)&xr[3][kq*4]);
        }
        red[w*4 + 0][lane] = acc0.x + acc0.y + acc0.z + acc0.w;
        red[w*4 + 1][lane] = acc1.x + acc1.y + acc1.z + acc1.w;
        red[w*4 + 2][lane] = acc2.x + acc2.y + acc2.z + acc2.w;
        red[w*4 + 3][lane] = acc3.x + acc3.y + acc3.z + acc3.w;
        __syncthreads();
        // finalize: thread (rr=w, hl=lane) -> output (r0row+rr, h0+hl)
        float s = red[w][lane] + red[4 + w][lane] + red[8 + w][lane] + red[12 + w][lane];
        if (edge) s += b1[h0 + lane];
        Out[(r0row + w) * HH + h0 + lane] = (_Float16)s;
        __syncthreads();                 // red consumed before next pass writes
    }
}

// ---------------------------------------------------------------------------
// k_pairs: 32x32 tile / block, 256 blocks (1/CU), 4x4 register blocking.
// fp16 LDS tiles; chunk-XOR swizzle pos(r,cc) = r*256 + ((cc ^ (r>>2))<<3):
//  - compute b128 reads: fixed cc across lanes -> slots (cc^q) distinct mod 8
//    -> 8 non-overlapping 4-bank groups x 8-lane broadcast = bandwidth floor.
// relu(a+c) packed fp16, fp32 accumulate via v_dot2_f32_f16.
// ---------------------------------------------------------------------------
#define CT 8192     // C-tile base (halves)
#define WT 16384    // w2 base (halves)

__device__ inline float dot8(h8 w, h8 a, h8 c, float acc) {
    h8 s = a + c;
    s = __builtin_elementwise_max(s, (h8)(_Float16)0.f);
    union { h8 v; h2 p[4]; } su, wu;
    su.v = s; wu.v = w;
    acc = __builtin_amdgcn_fdot2(su.p[0], wu.p[0], acc, false);
    acc = __builtin_amdgcn_fdot2(su.p[1], wu.p[1], acc, false);
    acc = __builtin_amdgcn_fdot2(su.p[2], wu.p[2], acc, false);
    acc = __builtin_amdgcn_fdot2(su.p[3], wu.p[3], acc, false);
    return acc;
}

__global__ __launch_bounds__(256) void k_pairs(
    const _Float16* __restrict__ A, const _Float16* __restrict__ C,
    const float* __restrict__ W2, const float* __restrict__ b2,
    float* __restrict__ out)
{
    __shared__ _Float16 lds[WT + 256];     // 33.3 KB
    const int t  = threadIdx.x;
    const int bx = blockIdx.x;
    const int tn0 = (bx >> 4) * 32;
    const int tm0 = (bx & 15) * 32;

    lds[WT + t] = (_Float16)W2[t];
    #pragma unroll
    for (int q = 0; q < 8; ++q) {
        int g   = q * 256 + t;             // 0..2047
        int row = g >> 5, cc = g & 31, r = row & 31;
        int dst = (row < 32 ? 0 : CT) + r * 256 + ((cc ^ (r >> 2)) << 3);
        const _Float16* src = (row < 32) ? A + (tn0 + r) * HH + cc * 8
                                         : C + (tm0 + r) * HH + cc * 8;
        *(h8*)&lds[dst] = *(const h8*)src;
    }
    __syncthreads();

    const int w  = t >> 6, lane = t & 63;
    const int qa = lane & 7,  ra = 4 * qa;   // A rows ra..ra+3 ((ra+i)>>2 == qa)
    const int qc = lane >> 3, rc = 4 * qc;   // C rows rc..rc+3
    const int h0 = w * 64;

    float acc[4][4];
    #pragma unroll
    for (int i = 0; i < 4; ++i)
        #pragma unroll
        for (int j = 0; j < 4; ++j) acc[i][j] = 0.f;

    #pragma unroll
    for (int hh = 0; hh < 64; hh += 8) {
        int h  = h0 + hh;
        int cc = h >> 3;
        int sa = (cc ^ qa) << 3;
        int sc = (cc ^ qc) << 3;
        h8 wv = *(const h8*)&lds[WT + h];
        h8 av[4], cv[4];
        #pragma unroll
        for (int i = 0; i < 4; ++i) av[i] = *(const h8*)&lds[(ra + i) * 256 + sa];
        #pragma unroll
        for (int j = 0; j < 4; ++j) cv[j] = *(const h8*)&lds[CT + (rc + j) * 256 + sc];
        #pragma unroll
        for (int i = 0; i < 4; ++i)
            #pragma unroll
            for (int j = 0; j < 4; ++j)
                acc[i][j] = dot8(wv, av[i], cv[j], acc[i][j]);
    }

    // cross-wave reduce: float rows of 36 (9 chunks) -> b128 stores/reads at
    // the LDS bandwidth floor. red region reuses tile space (w2 untouched).
    __syncthreads();
    float* red = (float*)lds;              // [w][32 rows][36], 18.4 KB
    #pragma unroll
    for (int i = 0; i < 4; ++i) {
        float4 f;
        f.x = acc[i][0]; f.y = acc[i][1]; f.z = acc[i][2]; f.w = acc[i][3];
        *(float4*)&red[w * 1152 + (ra + i) * 36 + rc] = f;
    }
    __syncthreads();

    const int rr = t >> 3;                 // 0..31
    const int c4 = (t & 7) * 4;            // 0,4,...,28
    v4f s = *(const v4f*)&red[rr * 36 + c4];
    s += *(const v4f*)&red[1152 + rr * 36 + c4];
    s += *(const v4f*)&red[2304 + rr * 36 + c4];
    s += *(const v4f*)&red[3456 + rr * 36 + c4];
    const float b2v = b2[0];
    float4 o;
    float* op = &o.x;
    #pragma unroll
    for (int k = 0; k < 4; ++k) {
        float logit = s[k] + b2v;
        float p = 1.0f / (1.0f + __expf(-logit));
        op[k] = fminf(fmaxf(p, 1e-6f), 1.0f - 1e-6f);
    }
    *(float4*)&out[(tn0 + rr) * MM + tm0 + c4] = o;
}

extern "C" void kernel_launch(void* const* d_in, const int* in_sizes, int n_in,
                              void* d_out, int out_size, void* d_ws, size_t ws_size,
                              hipStream_t stream)
{
    const float* X  = (const float*)d_in[0];
    const int*   V  = (const int*)d_in[1];
    const int*   E  = (const int*)d_in[2];
    const float* W1 = (const float*)d_in[3];
    const float* b1 = (const float*)d_in[4];
    const float* W2 = (const float*)d_in[5];
    const float* b2 = (const float*)d_in[6];

    _Float16* A = (_Float16*)d_ws;
    _Float16* C = A + NN * HH;
    float* out  = (float*)d_out;
    int ninc    = in_sizes[1];   // 8192

    k_stage<<<256, 256, 0, stream>>>(X, V, E, W1, b1, A, C, ninc);
    k_pairs<<<256, 256, 0, stream>>>(A, C, W2, b2, out);
}